// Round 18
// baseline (220.839 us; speedup 1.0000x reference)
//
#include <hip/hip_runtime.h>
#include <hip/hip_bf16.h>
#include <stdint.h>

// ---------- types ----------
typedef __bf16 bf16x8_t __attribute__((ext_vector_type(8)));
typedef float  f32x4_t  __attribute__((ext_vector_type(4)));
typedef short  short8_t __attribute__((ext_vector_type(8)));

__device__ __forceinline__ unsigned short f2b(float f) {
    union { float f; unsigned u; } v; v.f = f;
    unsigned u = v.u;
    return (unsigned short)((u + 0x7FFFu + ((u >> 16) & 1u)) >> 16);
}
__device__ __forceinline__ float b2f(unsigned short b) {
    union { unsigned u; float f; } v; v.u = ((unsigned)b) << 16; return v.f;
}

#define AS3(p) ((__attribute__((address_space(3))) void*)(p))
#define AS1(p) ((const __attribute__((address_space(1))) void*)(p))
#define FENCE() asm volatile("" ::: "memory")

// ---------- constants ----------
#define NB   16
#define CIN  512
#define MMID 256
#define HW   4096
#define KSPLIT 4
#define ASZ  (128 * 64)      // 128-tile LDS buffer elems
#define A4E  (256 * 32)      // bn128 A buffer elems (16 KB)
#define B4E  (128 * 32)      // bn128 B buffer elems (8 KB)

// XCD-chunked bijective swizzle (nwg % 8 == 0 for all grids), gy fastest
__device__ __forceinline__ void swz3(int gx, int gy, int& bx, int& by, int& bz) {
    const int nwg = gridDim.x, ord = blockIdx.x, q = nwg >> 3;
    const int s = (ord & 7) * q + (ord >> 3);
    by = s % gy;
    const int rem = s / gy;
    bx = rem % gx;
    bz = rem / gx;
}

// ---------- weight prep ----------
__global__ __launch_bounds__(256) void prep_weights(
    const float* __restrict__ Ws, const float* __restrict__ Wp,
    const float* __restrict__ Wef, const float* __restrict__ bs,
    const float* __restrict__ bp,
    unsigned short* __restrict__ Wsp, unsigned short* __restrict__ Wex,
    unsigned short* __restrict__ WpT, float* __restrict__ bsp)
{
    int i = blockIdx.x * 256 + threadIdx.x;
    if (i < MMID * CIN) {
        Wsp[i]              = f2b(Ws[i]);
        Wsp[MMID * CIN + i] = f2b(Wp[i]);
        Wex[i]              = f2b(Wef[i]);
        const int c = i >> 8, k = i & (MMID - 1);
        WpT[i] = f2b(Wp[(size_t)k * CIN + c]);
    }
    if (i < MMID) { bsp[i] = bs[i]; bsp[MMID + i] = bp[i]; }
}

// ---------- x [n][512][4096] f32 -> xT [n][4096][512] bf16 ----------
__global__ __launch_bounds__(256) void transpose_convert_x(
    const float* __restrict__ x, unsigned short* __restrict__ xT)
{
    __shared__ unsigned short tile[64][66];
    const int n = blockIdx.z, c0 = blockIdx.y * 64, h0 = blockIdx.x * 64;
    const float* s = x + ((size_t)n * CIN + c0) * HW + h0;
    unsigned short* d = xT + ((size_t)n * HW + h0) * CIN + c0;
    const int t = threadIdx.x;
    {
        const int rr = t >> 4, cc = (t & 15) * 4;
        #pragma unroll
        for (int p = 0; p < 4; ++p) {
            int r = p * 16 + rr;
            float4 v = *(const float4*)(s + (size_t)r * HW + cc);
            tile[r][cc + 0] = f2b(v.x); tile[r][cc + 1] = f2b(v.y);
            tile[r][cc + 2] = f2b(v.z); tile[r][cc + 3] = f2b(v.w);
        }
    }
    __syncthreads();
    {
        const int wr = t >> 3, wc = (t & 7) * 8;
        #pragma unroll
        for (int p = 0; p < 2; ++p) {
            int h = p * 32 + wr;
            unsigned short tmp[8];
            #pragma unroll
            for (int j = 0; j < 8; ++j) tmp[j] = tile[wc + j][h];
            *(short8_t*)(d + (size_t)h * CIN + wc) = *(const short8_t*)tmp;
        }
    }
}

// ---------- generic bf16 64x64-tile transpose (attnT only) ----------
__global__ __launch_bounds__(256) void transpose_bf16_64(
    const unsigned short* __restrict__ src, unsigned short* __restrict__ dst,
    int srs, int drs, long long sbs, long long dbs)
{
    __shared__ unsigned short tile[64][66];
    const int n = blockIdx.z, r0 = blockIdx.y * 64, c0 = blockIdx.x * 64;
    const unsigned short* s = src + (size_t)n * sbs + (size_t)r0 * srs + c0;
    unsigned short* d = dst + (size_t)n * dbs + (size_t)c0 * drs + r0;
    const int t = threadIdx.x;
    const int rr = t >> 3, cc = (t & 7) * 8;
    #pragma unroll
    for (int p = 0; p < 2; ++p) {
        int r = p * 32 + rr;
        short8_t v = *(const short8_t*)(s + (size_t)r * srs + cc);
        #pragma unroll
        for (int j = 0; j < 8; ++j) tile[r][cc + j] = ((const unsigned short*)&v)[j];
    }
    __syncthreads();
    #pragma unroll
    for (int p = 0; p < 2; ++p) {
        int c = p * 32 + rr;
        unsigned short tmp[8];
        #pragma unroll
        for (int j = 0; j < 8; ++j) tmp[j] = tile[cc + j][c];
        *(short8_t*)(d + (size_t)c * drs + cc) = *(const short8_t*)tmp;
    }
}

// ---------- coalesced LDS-repack epilogue (128-tile kernels) ----------
// EPI: 1 = f32; 2 = bf16; 4 = bf16 + identity (Meff + I)
template <int EPI>
__device__ __forceinline__ void epilogue_repack(
    f32x4_t (&acc)[4][4], unsigned short* smem,
    int m0, int n0, int wave, int lane,
    void* __restrict__ Cout, int ldc, size_t cbase)
{
    float* fbuf = (float*)smem;
    const int t   = wave * 64 + lane;
    const int l15 = lane & 15, l16 = lane >> 4;
    const int wr2 = wave >> 1;
    const int wc  = (wave & 1) * 64;

    #pragma unroll
    for (int p = 0; p < 4; ++p) {
        __syncthreads();
        if (wr2 == (p >> 1)) {
            const int ihalf = p & 1;
            #pragma unroll
            for (int i2 = 0; i2 < 2; ++i2) {
                const int i = ihalf * 2 + i2;
                #pragma unroll
                for (int r = 0; r < 4; ++r) {
                    const int lrow = i2 * 16 + l16 * 4 + r;
                    #pragma unroll
                    for (int j = 0; j < 4; ++j)
                        fbuf[lrow * 132 + wc + j * 16 + l15] = acc[i][j][r];
                }
            }
        }
        __syncthreads();
        #pragma unroll
        for (int it = 0; it < 2; ++it) {
            const int lrow = it * 16 + (t >> 4);
            const int col  = (t & 15) * 8;
            const int row  = m0 + p * 32 + lrow;
            float v[8];
            *(float4*)&v[0] = *(const float4*)&fbuf[lrow * 132 + col];
            *(float4*)&v[4] = *(const float4*)&fbuf[lrow * 132 + col + 4];
            const size_t idx = cbase + (size_t)row * ldc + n0 + col;
            if constexpr (EPI == 1) {
                float* op = (float*)Cout + idx;
                *(float4*)op = *(const float4*)&v[0];
                *(float4*)(op + 4) = *(const float4*)&v[4];
            } else if constexpr (EPI == 4) {
                unsigned short o[8];
                #pragma unroll
                for (int k = 0; k < 8; ++k)
                    o[k] = f2b(v[k] + ((row == n0 + col + k) ? 1.0f : 0.0f));
                *(short8_t*)((unsigned short*)Cout + idx) = *(const short8_t*)o;
            } else {
                unsigned short o[8];
                #pragma unroll
                for (int k = 0; k < 8; ++k) o[k] = f2b(v[k]);
                *(short8_t*)((unsigned short*)Cout + idx) = *(const short8_t*)o;
            }
        }
    }
}

// ---------- counted-vmcnt double-buffered K-loop, raw barriers (128-tile) ----------
#define GEMM_KLOOP(Ab, Bb, lda, ldb, KBEG, NT)                                          \
    auto stage = [&](int k0, int b) {                                                   \
        unsigned short* Asb = smem + b * 2 * ASZ;                                       \
        unsigned short* Bsb = Asb + ASZ;                                                \
        _Pragma("unroll")                                                               \
        for (int c = 0; c < 4; ++c) {                                                   \
            const int o   = (c * 256 + t) * 16;                                         \
            const int row = o >> 7;                                                     \
            const int ce  = ((o & 127) ^ ((row & 7) << 4)) >> 1;                        \
            __builtin_amdgcn_global_load_lds(                                           \
                AS1(Ab + (size_t)row * lda + k0 + ce), AS3((char*)Asb + o), 16, 0, 0);  \
            __builtin_amdgcn_global_load_lds(                                           \
                AS1(Bb + (size_t)row * ldb + k0 + ce), AS3((char*)Bsb + o), 16, 0, 0);  \
        }                                                                               \
    };                                                                                  \
    stage(KBEG, 0);                                                                     \
    for (int itk = 0; itk < (NT); ++itk) {                                              \
        const int cur = itk & 1;                                                        \
        if (itk + 1 < (NT)) {                                                           \
            stage(KBEG + (itk + 1) * 64, cur ^ 1);                                      \
            asm volatile("s_waitcnt vmcnt(8)" ::: "memory");                            \
        } else {                                                                        \
            asm volatile("s_waitcnt vmcnt(0)" ::: "memory");                            \
        }                                                                               \
        __builtin_amdgcn_s_barrier();                                                   \
        FENCE();                                                                        \
        const char* Asb = (const char*)(smem + cur * 2 * ASZ);                          \
        const char* Bsb = Asb + 2 * ASZ;                                                \
        const int swz = (l15 & 7) << 4;                                                 \
        _Pragma("unroll")                                                               \
        for (int ks = 0; ks < 2; ++ks) {                                                \
            bf16x8_t af[4], bfr[4];                                                     \
            const int cb = (ks * 64 + l16 * 16) ^ swz;                                  \
            _Pragma("unroll")                                                           \
            for (int i = 0; i < 4; ++i) {                                               \
                af[i]  = *(const bf16x8_t*)(Asb + (wr + i * 16 + l15) * 128 + cb);      \
                bfr[i] = *(const bf16x8_t*)(Bsb + (wc + i * 16 + l15) * 128 + cb);      \
            }                                                                           \
            _Pragma("unroll")                                                           \
            for (int i = 0; i < 4; ++i)                                                 \
                _Pragma("unroll")                                                       \
                for (int j = 0; j < 4; ++j)                                             \
                    acc[i][j] = __builtin_amdgcn_mfma_f32_16x16x32_bf16(                \
                        af[i], bfr[j], acc[i][j], 0, 0, 0);                             \
        }                                                                               \
        FENCE();                                                                        \
        __builtin_amdgcn_s_barrier();                                                   \
        FENCE();                                                                        \
    }

// ---------- gemm_bn128: BM=256, BN=128, BK=32, 512 thr (8 waves 4Mx2N) ----------
// 48 KB LDS (2 x (16K A + 8K B)) -> 3 blocks/CU; halves A re-staging vs BN=64.
// Counted vmcnt(3) (3 gloads/thread/step), raw barriers, (row&3)<<4 XOR swizzle.
// EPI 0: bf16 + bias[row]; EPI 1: f32 + bias[row] (per-batch via bias_bstride).
template <int EPI>
__global__ __launch_bounds__(512, 3) void gemm_bn128(
    const unsigned short* __restrict__ A, const unsigned short* __restrict__ B,
    long long strideA, long long strideB,
    const float* __restrict__ bias, int bias_bstride,
    void* __restrict__ Cout, int ldc, long long strideC,
    int gx, int gy)
{
    __shared__ unsigned short smem[2 * (A4E + B4E)];   // 48 KB

    int bx, by, n;  swz3(gx, gy, bx, by, n);   // by (M-tile) fastest
    const int m0 = by * 256;
    const int n0 = bx * 128;

    const unsigned short* Ab = A + (size_t)n * strideA + (size_t)m0 * CIN;
    const unsigned short* Bb = B + (size_t)n * strideB + (size_t)n0 * CIN;

    const int t    = threadIdx.x;
    const int lane = t & 63;
    const int wave = t >> 6;              // 0..7
    const int wr   = (wave >> 1) * 64;    // 4 M-groups of 64 rows
    const int wc   = (wave & 1) * 64;     // 2 N-groups of 64 cols
    const int l15  = lane & 15;
    const int l16  = lane >> 4;

    f32x4_t acc[4][4] = {};

    auto stage = [&](int k0, int b) {
        unsigned short* Asb = smem + b * (A4E + B4E);
        unsigned short* Bsb = Asb + A4E;
        #pragma unroll
        for (int c = 0; c < 2; ++c) {       // A: 16 KB (256 rows x 64 B)
            const int ci  = c * 512 + t;
            const int row = ci >> 2;
            const int ce  = (((ci & 3) * 16) ^ ((row & 3) << 4)) >> 1;
            __builtin_amdgcn_global_load_lds(
                AS1(Ab + (size_t)row * CIN + k0 + ce), AS3((char*)Asb + ci * 16), 16, 0, 0);
        }
        {                                    // B: 8 KB (128 rows x 64 B)
            const int ci  = t;
            const int row = ci >> 2;
            const int ce  = (((ci & 3) * 16) ^ ((row & 3) << 4)) >> 1;
            __builtin_amdgcn_global_load_lds(
                AS1(Bb + (size_t)row * CIN + k0 + ce), AS3((char*)Bsb + ci * 16), 16, 0, 0);
        }
    };

    const int NT = CIN / 32;   // K = 512, BK = 32 -> 16 steps
    stage(0, 0);
    for (int itk = 0; itk < NT; ++itk) {
        const int cur = itk & 1;
        if (itk + 1 < NT) {
            stage((itk + 1) * 32, cur ^ 1);
            asm volatile("s_waitcnt vmcnt(3)" ::: "memory");
        } else {
            asm volatile("s_waitcnt vmcnt(0)" ::: "memory");
        }
        __builtin_amdgcn_s_barrier();
        FENCE();
        const char* Asb = (const char*)(smem + cur * (A4E + B4E));
        const char* Bsb = Asb + 2 * A4E;
        bf16x8_t af[4], bfr[4];
        #pragma unroll
        for (int i = 0; i < 4; ++i) {
            const int row = wr + i * 16 + l15;
            af[i] = *(const bf16x8_t*)(Asb + row * 64 + ((l16 * 16) ^ ((row & 3) << 4)));
        }
        #pragma unroll
        for (int j = 0; j < 4; ++j) {
            const int row = wc + j * 16 + l15;
            bfr[j] = *(const bf16x8_t*)(Bsb + row * 64 + ((l16 * 16) ^ ((row & 3) << 4)));
        }
        __builtin_amdgcn_s_setprio(1);
        #pragma unroll
        for (int i = 0; i < 4; ++i)
            #pragma unroll
            for (int j = 0; j < 4; ++j)
                acc[i][j] = __builtin_amdgcn_mfma_f32_16x16x32_bf16(
                    af[i], bfr[j], acc[i][j], 0, 0, 0);
        __builtin_amdgcn_s_setprio(0);
        FENCE();
        __builtin_amdgcn_s_barrier();
        FENCE();
    }

    // epilogue: 8 passes of 32 rows x 128 cols via LDS repack (fbuf 32x132 f32)
    float* fbuf = (float*)smem;
    const size_t cbase = (size_t)n * strideC;
    const float* beff = bias + (size_t)n * bias_bstride;
    #pragma unroll
    for (int p = 0; p < 8; ++p) {
        __syncthreads();
        if ((wave >> 1) == (p >> 1)) {
            #pragma unroll
            for (int i2 = 0; i2 < 2; ++i2) {
                const int i = (p & 1) * 2 + i2;
                #pragma unroll
                for (int r = 0; r < 4; ++r) {
                    const int lrow = i2 * 16 + l16 * 4 + r;
                    #pragma unroll
                    for (int j = 0; j < 4; ++j)
                        fbuf[lrow * 132 + wc + j * 16 + l15] = acc[i][j][r];
                }
            }
        }
        __syncthreads();
        const int lrow = t >> 4;           // 0..31
        const int col  = (t & 15) * 8;     // 0..120
        const int row  = m0 + p * 32 + lrow;
        float v[8];
        *(float4*)&v[0] = *(const float4*)&fbuf[lrow * 132 + col];
        *(float4*)&v[4] = *(const float4*)&fbuf[lrow * 132 + col + 4];
        const float badd = beff[row];
        const size_t idx = cbase + (size_t)row * ldc + n0 + col;
        if constexpr (EPI == 1) {
            float o[8];
            #pragma unroll
            for (int k = 0; k < 8; ++k) o[k] = v[k] + badd;
            float* op = (float*)Cout + idx;
            *(float4*)op = *(const float4*)&o[0];
            *(float4*)(op + 4) = *(const float4*)&o[4];
        } else {
            unsigned short o[8];
            #pragma unroll
            for (int k = 0; k < 8; ++k) o[k] = f2b(v[k] + badd);
            *(short8_t*)((unsigned short*)Cout + idx) = *(const short8_t*)o;
        }
    }
}

// ---------- scores GEMM, split-K=4 (128-tile) ----------
__global__ __launch_bounds__(256) void gemm_scores(
    const unsigned short* __restrict__ Ysp, float* __restrict__ scoresP)
{
    __shared__ unsigned short smem[4 * ASZ];

    int bx, by, z;  swz3(MMID / 128, MMID / 128, bx, by, z);
    const int n  = z >> 2;
    const int kc = z & 3;
    const int m0 = by * 128;
    const int n0 = bx * 128;

    const unsigned short* Ab = Ysp + (size_t)n * CIN * HW + (size_t)m0 * HW;
    const unsigned short* Bb = Ysp + (size_t)n * CIN * HW + (size_t)(MMID + n0) * HW;

    const int t    = threadIdx.x;
    const int lane = t & 63;
    const int wave = t >> 6;
    const int wr   = (wave >> 1) * 64;
    const int wc   = (wave & 1) * 64;
    const int l15  = lane & 15;
    const int l16  = lane >> 4;

    f32x4_t acc[4][4] = {};
    const int kbeg = kc * (HW / KSPLIT);
    GEMM_KLOOP(Ab, Bb, HW, HW, kbeg, (HW / KSPLIT) / 64)

    float* outp = scoresP + (size_t)(kc * NB + n) * MMID * MMID;
    epilogue_repack<1>(acc, smem, m0, n0, wave, lane, outp, MMID, 0);
}

// ---------- softmax over rows (reduces KSPLIT partials, scale 1/64) ----------
__global__ __launch_bounds__(256) void softmax_rows(
    const float* __restrict__ scoresP, unsigned short* __restrict__ attn)
{
    const int wave = threadIdx.x >> 6;
    const int l    = threadIdx.x & 63;
    const size_t row = (size_t)blockIdx.x * 4 + wave;
    const size_t pstride = (size_t)NB * MMID * MMID;
    float4 v = {0.f, 0.f, 0.f, 0.f};
    #pragma unroll
    for (int p = 0; p < KSPLIT; ++p) {
        float4 u = *(const float4*)(scoresP + p * pstride + row * MMID + l * 4);
        v.x += u.x; v.y += u.y; v.z += u.z; v.w += u.w;
    }
    float mx = fmaxf(fmaxf(v.x, v.y), fmaxf(v.z, v.w));
    #pragma unroll
    for (int off = 32; off; off >>= 1) mx = fmaxf(mx, __shfl_xor(mx, off));
    const float sc = 0.015625f;               // 1/64
    float e0 = __expf((v.x - mx) * sc), e1 = __expf((v.y - mx) * sc);
    float e2 = __expf((v.z - mx) * sc), e3 = __expf((v.w - mx) * sc);
    float sum = e0 + e1 + e2 + e3;
    #pragma unroll
    for (int off = 32; off; off >>= 1) sum += __shfl_xor(sum, off);
    const float inv = 1.0f / sum;
    unsigned short o[4] = { f2b(e0 * inv), f2b(e1 * inv), f2b(e2 * inv), f2b(e3 * inv) };
    *(uint64_t*)(attn + row * MMID + l * 4) = *(const uint64_t*)o;
}

// ---------- vec[n][c] = be[c] + sum_k G[n][c][k] * bp[k] ----------
__global__ __launch_bounds__(256) void compute_vec(
    const unsigned short* __restrict__ G, const float* __restrict__ bsp,
    const float* __restrict__ be, float* __restrict__ vec)
{
    const int n = blockIdx.x >> 1;
    const int c = ((blockIdx.x & 1) << 8) + threadIdx.x;
    const unsigned short* g = G + ((size_t)n * CIN + c) * MMID;
    float s = 0.f;
    for (int k = 0; k < MMID; k += 8) {
        short8_t v = *(const short8_t*)(g + k);
        #pragma unroll
        for (int j = 0; j < 8; ++j)
            s += b2f((unsigned short)v[j]) * bsp[MMID + k + j];
    }
    vec[n * CIN + c] = be[c] + s;
}

// ---------- NT GEMM (128-tile): D[m][n] = sum_k A[m][k] * B[n][k] ----------
template <int EPI>
__global__ __launch_bounds__(256) void gemm_nt(
    const unsigned short* __restrict__ A, const unsigned short* __restrict__ B,
    int lda, int ldb, int K,
    long long strideA, long long strideB,
    void* __restrict__ Cout, int ldc, long long strideC,
    int gx, int gy)
{
    __shared__ unsigned short smem[4 * ASZ];

    int bx, by, n;  swz3(gx, gy, bx, by, n);
    const int m0 = by * 128;
    const int n0 = bx * 128;

    const unsigned short* Ab = A + (size_t)n * strideA + (size_t)m0 * lda;
    const unsigned short* Bb = B + (size_t)n * strideB + (size_t)n0 * ldb;

    const int t    = threadIdx.x;
    const int lane = t & 63;
    const int wave = t >> 6;
    const int wr   = (wave >> 1) * 64;
    const int wc   = (wave & 1) * 64;
    const int l15  = lane & 15;
    const int l16  = lane >> 4;

    f32x4_t acc[4][4] = {};
    GEMM_KLOOP(Ab, Bb, lda, ldb, 0, K / 64)

    epilogue_repack<EPI>(acc, smem, m0, n0, wave, lane,
                         Cout, ldc, (size_t)n * strideC);
}

// ---------- launch ----------
extern "C" void kernel_launch(void* const* d_in, const int* in_sizes, int n_in,
                              void* d_out, int out_size, void* d_ws, size_t ws_size,
                              hipStream_t stream)
{
    const float* x   = (const float*)d_in[0];
    const float* Ws  = (const float*)d_in[1];
    const float* bs  = (const float*)d_in[2];
    const float* Wp  = (const float*)d_in[3];
    const float* bp  = (const float*)d_in[4];
    const float* Wef = (const float*)d_in[5];
    const float* be  = (const float*)d_in[6];
    float* out = (float*)d_out;

    unsigned short* xT   = (unsigned short*)d_ws;                         // [16][4096][512] bf16
    unsigned short* Ysp  = xT   + (size_t)NB * HW * CIN;                  // [16][512][4096] bf16
    unsigned short* Wsp  = Ysp  + (size_t)NB * CIN * HW;                  // [512][512] bf16
    unsigned short* Wex  = Wsp  + (size_t)CIN * CIN;                      // [512][256] bf16
    unsigned short* WpT  = Wex  + (size_t)CIN * MMID;                     // [512][256] bf16
    unsigned short* attn = WpT  + (size_t)CIN * MMID;                     // [16][256][256] bf16
    unsigned short* attnT= attn + (size_t)NB * MMID * MMID;               // [16][256][256] bf16
    unsigned short* G    = attnT+ (size_t)NB * MMID * MMID;               // [16][512][256] bf16
    unsigned short* Meff = G    + (size_t)NB * CIN * MMID;                // [16][512][512] bf16
    float* scoresP = (float*)(Meff + (size_t)NB * CIN * CIN);             // [4][16][256][256] f32
    float* bsp = scoresP + (size_t)KSPLIT * NB * MMID * MMID;             // [512]
    float* vec = bsp + CIN;                                               // [16][512]

    prep_weights<<<512, 256, 0, stream>>>(Ws, Wp, Wef, bs, bp, Wsp, Wex, WpT, bsp);

    transpose_convert_x<<<dim3(HW / 64, CIN / 64, NB), 256, 0, stream>>>(x, xT);

    // Ysp[mm][h] = Wsp[mm][c].xT[h][c] + bsp[mm]   (BM=256, BN=128, 3 blocks/CU)
    gemm_bn128<0><<<(CIN / 256) * (HW / 128) * NB, 512, 0, stream>>>(
        Wsp, xT, 0LL, (long long)HW * CIN,
        bsp, 0, Ysp, HW, (long long)CIN * HW,
        HW / 128, CIN / 256);

    // scores partials, split-K=4
    gemm_scores<<<(MMID / 128) * (MMID / 128) * NB * KSPLIT, 256, 0, stream>>>(
        Ysp, scoresP);

    softmax_rows<<<NB * MMID / 4, 256, 0, stream>>>(scoresP, attn);

    // attnT[k][m] = attn[m][k]
    transpose_bf16_64<<<dim3(MMID / 64, MMID / 64, NB), 256, 0, stream>>>(
        attn, attnT, MMID, MMID, (long long)MMID * MMID, (long long)MMID * MMID);

    // G[c][k] = Wex[c][m] . attnT[k][m]   (M=512, N=256, K=256) = W_ext @ attn
    gemm_nt<2><<<(MMID / 128) * (CIN / 128) * NB, 256, 0, stream>>>(
        Wex, attnT, MMID, MMID, MMID,
        0LL, (long long)MMID * MMID,
        G, MMID, (long long)CIN * MMID,
        MMID / 128, CIN / 128);

    // vec[n][c] = be[c] + G[n][c][:] . bp
    compute_vec<<<NB * 2, 256, 0, stream>>>(G, bsp, be, vec);

    // Meff[c][c'] = G[c][k].WpT[c'][k] + I   (residual folded into diagonal)
    gemm_nt<4><<<(CIN / 128) * (CIN / 128) * NB, 256, 0, stream>>>(
        G, WpT, MMID, MMID, MMID,
        (long long)CIN * MMID, 0LL,
        Meff, CIN, (long long)CIN * CIN,
        CIN / 128, CIN / 128);

    // out[c][h] = (Meff+I)[c][c'] . xT[h][c'] + vec[n][c]   (f32 store)
    gemm_bn128<1><<<(CIN / 256) * (HW / 128) * NB, 512, 0, stream>>>(
        Meff, xT, (long long)CIN * CIN, (long long)HW * CIN,
        vec, CIN, out, HW, (long long)CIN * HW,
        HW / 128, CIN / 256);
}

// Round 19
// 197.005 us; speedup vs baseline: 1.1210x; 1.1210x over previous
//
#include <hip/hip_runtime.h>
#include <hip/hip_bf16.h>
#include <stdint.h>

// ---------- types ----------
typedef __bf16 bf16x8_t __attribute__((ext_vector_type(8)));
typedef float  f32x4_t  __attribute__((ext_vector_type(4)));
typedef short  short8_t __attribute__((ext_vector_type(8)));

__device__ __forceinline__ unsigned short f2b(float f) {
    union { float f; unsigned u; } v; v.f = f;
    unsigned u = v.u;
    return (unsigned short)((u + 0x7FFFu + ((u >> 16) & 1u)) >> 16);
}
__device__ __forceinline__ float b2f(unsigned short b) {
    union { unsigned u; float f; } v; v.u = ((unsigned)b) << 16; return v.f;
}

#define AS3(p) ((__attribute__((address_space(3))) void*)(p))
#define AS1(p) ((const __attribute__((address_space(1))) void*)(p))
#define FENCE() asm volatile("" ::: "memory")

// ---------- constants ----------
#define NB   16
#define CIN  512
#define MMID 256
#define HW   4096
#define KSPLIT 4
#define ASZ  (128 * 64)      // 128-tile LDS buffer elems
#define ASZA3 (256 * 64)     // occ2 A buffer elems (32 KB)
#define ASZB3 (64 * 64)      // occ2 B buffer elems (8 KB)

// XCD-chunked bijective swizzle (nwg % 8 == 0 for all grids), gy fastest
__device__ __forceinline__ void swz3(int gx, int gy, int& bx, int& by, int& bz) {
    const int nwg = gridDim.x, ord = blockIdx.x, q = nwg >> 3;
    const int s = (ord & 7) * q + (ord >> 3);
    by = s % gy;
    const int rem = s / gy;
    bx = rem % gx;
    bz = rem / gx;
}

// ---------- weight prep ----------
__global__ __launch_bounds__(256) void prep_weights(
    const float* __restrict__ Ws, const float* __restrict__ Wp,
    const float* __restrict__ Wef, const float* __restrict__ bs,
    const float* __restrict__ bp,
    unsigned short* __restrict__ Wsp, unsigned short* __restrict__ Wex,
    unsigned short* __restrict__ WpT, float* __restrict__ bsp)
{
    int i = blockIdx.x * 256 + threadIdx.x;
    if (i < MMID * CIN) {
        Wsp[i]              = f2b(Ws[i]);
        Wsp[MMID * CIN + i] = f2b(Wp[i]);
        Wex[i]              = f2b(Wef[i]);
        const int c = i >> 8, k = i & (MMID - 1);
        WpT[i] = f2b(Wp[(size_t)k * CIN + c]);
    }
    if (i < MMID) { bsp[i] = bs[i]; bsp[MMID + i] = bp[i]; }
}

// ---------- x [n][512][4096] f32 -> xT [n][4096][512] bf16 ----------
__global__ __launch_bounds__(256) void transpose_convert_x(
    const float* __restrict__ x, unsigned short* __restrict__ xT)
{
    __shared__ unsigned short tile[64][66];
    const int n = blockIdx.z, c0 = blockIdx.y * 64, h0 = blockIdx.x * 64;
    const float* s = x + ((size_t)n * CIN + c0) * HW + h0;
    unsigned short* d = xT + ((size_t)n * HW + h0) * CIN + c0;
    const int t = threadIdx.x;
    {
        const int rr = t >> 4, cc = (t & 15) * 4;
        #pragma unroll
        for (int p = 0; p < 4; ++p) {
            int r = p * 16 + rr;
            float4 v = *(const float4*)(s + (size_t)r * HW + cc);
            tile[r][cc + 0] = f2b(v.x); tile[r][cc + 1] = f2b(v.y);
            tile[r][cc + 2] = f2b(v.z); tile[r][cc + 3] = f2b(v.w);
        }
    }
    __syncthreads();
    {
        const int wr = t >> 3, wc = (t & 7) * 8;
        #pragma unroll
        for (int p = 0; p < 2; ++p) {
            int h = p * 32 + wr;
            unsigned short tmp[8];
            #pragma unroll
            for (int j = 0; j < 8; ++j) tmp[j] = tile[wc + j][h];
            *(short8_t*)(d + (size_t)h * CIN + wc) = *(const short8_t*)tmp;
        }
    }
}

// ---------- generic bf16 64x64-tile transpose (attnT only) ----------
__global__ __launch_bounds__(256) void transpose_bf16_64(
    const unsigned short* __restrict__ src, unsigned short* __restrict__ dst,
    int srs, int drs, long long sbs, long long dbs)
{
    __shared__ unsigned short tile[64][66];
    const int n = blockIdx.z, r0 = blockIdx.y * 64, c0 = blockIdx.x * 64;
    const unsigned short* s = src + (size_t)n * sbs + (size_t)r0 * srs + c0;
    unsigned short* d = dst + (size_t)n * dbs + (size_t)c0 * drs + r0;
    const int t = threadIdx.x;
    const int rr = t >> 3, cc = (t & 7) * 8;
    #pragma unroll
    for (int p = 0; p < 2; ++p) {
        int r = p * 32 + rr;
        short8_t v = *(const short8_t*)(s + (size_t)r * srs + cc);
        #pragma unroll
        for (int j = 0; j < 8; ++j) tile[r][cc + j] = ((const unsigned short*)&v)[j];
    }
    __syncthreads();
    #pragma unroll
    for (int p = 0; p < 2; ++p) {
        int c = p * 32 + rr;
        unsigned short tmp[8];
        #pragma unroll
        for (int j = 0; j < 8; ++j) tmp[j] = tile[cc + j][c];
        *(short8_t*)(d + (size_t)c * drs + cc) = *(const short8_t*)tmp;
    }
}

// ---------- coalesced LDS-repack epilogue (128-tile kernels) ----------
// EPI: 1 = f32; 2 = bf16; 4 = bf16 + identity (Meff + I)
template <int EPI>
__device__ __forceinline__ void epilogue_repack(
    f32x4_t (&acc)[4][4], unsigned short* smem,
    int m0, int n0, int wave, int lane,
    void* __restrict__ Cout, int ldc, size_t cbase)
{
    float* fbuf = (float*)smem;
    const int t   = wave * 64 + lane;
    const int l15 = lane & 15, l16 = lane >> 4;
    const int wr2 = wave >> 1;
    const int wc  = (wave & 1) * 64;

    #pragma unroll
    for (int p = 0; p < 4; ++p) {
        __syncthreads();
        if (wr2 == (p >> 1)) {
            const int ihalf = p & 1;
            #pragma unroll
            for (int i2 = 0; i2 < 2; ++i2) {
                const int i = ihalf * 2 + i2;
                #pragma unroll
                for (int r = 0; r < 4; ++r) {
                    const int lrow = i2 * 16 + l16 * 4 + r;
                    #pragma unroll
                    for (int j = 0; j < 4; ++j)
                        fbuf[lrow * 132 + wc + j * 16 + l15] = acc[i][j][r];
                }
            }
        }
        __syncthreads();
        #pragma unroll
        for (int it = 0; it < 2; ++it) {
            const int lrow = it * 16 + (t >> 4);
            const int col  = (t & 15) * 8;
            const int row  = m0 + p * 32 + lrow;
            float v[8];
            *(float4*)&v[0] = *(const float4*)&fbuf[lrow * 132 + col];
            *(float4*)&v[4] = *(const float4*)&fbuf[lrow * 132 + col + 4];
            const size_t idx = cbase + (size_t)row * ldc + n0 + col;
            if constexpr (EPI == 1) {
                float* op = (float*)Cout + idx;
                *(float4*)op = *(const float4*)&v[0];
                *(float4*)(op + 4) = *(const float4*)&v[4];
            } else if constexpr (EPI == 4) {
                unsigned short o[8];
                #pragma unroll
                for (int k = 0; k < 8; ++k)
                    o[k] = f2b(v[k] + ((row == n0 + col + k) ? 1.0f : 0.0f));
                *(short8_t*)((unsigned short*)Cout + idx) = *(const short8_t*)o;
            } else {
                unsigned short o[8];
                #pragma unroll
                for (int k = 0; k < 8; ++k) o[k] = f2b(v[k]);
                *(short8_t*)((unsigned short*)Cout + idx) = *(const short8_t*)o;
            }
        }
    }
}

// ---------- counted-vmcnt double-buffered K-loop, raw barriers (128-tile) ----------
#define GEMM_KLOOP(Ab, Bb, lda, ldb, KBEG, NT)                                          \
    auto stage = [&](int k0, int b) {                                                   \
        unsigned short* Asb = smem + b * 2 * ASZ;                                       \
        unsigned short* Bsb = Asb + ASZ;                                                \
        _Pragma("unroll")                                                               \
        for (int c = 0; c < 4; ++c) {                                                   \
            const int o   = (c * 256 + t) * 16;                                         \
            const int row = o >> 7;                                                     \
            const int ce  = ((o & 127) ^ ((row & 7) << 4)) >> 1;                        \
            __builtin_amdgcn_global_load_lds(                                           \
                AS1(Ab + (size_t)row * lda + k0 + ce), AS3((char*)Asb + o), 16, 0, 0);  \
            __builtin_amdgcn_global_load_lds(                                           \
                AS1(Bb + (size_t)row * ldb + k0 + ce), AS3((char*)Bsb + o), 16, 0, 0);  \
        }                                                                               \
    };                                                                                  \
    stage(KBEG, 0);                                                                     \
    for (int itk = 0; itk < (NT); ++itk) {                                              \
        const int cur = itk & 1;                                                        \
        if (itk + 1 < (NT)) {                                                           \
            stage(KBEG + (itk + 1) * 64, cur ^ 1);                                      \
            asm volatile("s_waitcnt vmcnt(8)" ::: "memory");                            \
        } else {                                                                        \
            asm volatile("s_waitcnt vmcnt(0)" ::: "memory");                            \
        }                                                                               \
        __builtin_amdgcn_s_barrier();                                                   \
        FENCE();                                                                        \
        const char* Asb = (const char*)(smem + cur * 2 * ASZ);                          \
        const char* Bsb = Asb + 2 * ASZ;                                                \
        const int swz = (l15 & 7) << 4;                                                 \
        _Pragma("unroll")                                                               \
        for (int ks = 0; ks < 2; ++ks) {                                                \
            bf16x8_t af[4], bfr[4];                                                     \
            const int cb = (ks * 64 + l16 * 16) ^ swz;                                  \
            _Pragma("unroll")                                                           \
            for (int i = 0; i < 4; ++i) {                                               \
                af[i]  = *(const bf16x8_t*)(Asb + (wr + i * 16 + l15) * 128 + cb);      \
                bfr[i] = *(const bf16x8_t*)(Bsb + (wc + i * 16 + l15) * 128 + cb);      \
            }                                                                           \
            _Pragma("unroll")                                                           \
            for (int i = 0; i < 4; ++i)                                                 \
                _Pragma("unroll")                                                       \
                for (int j = 0; j < 4; ++j)                                             \
                    acc[i][j] = __builtin_amdgcn_mfma_f32_16x16x32_bf16(                \
                        af[i], bfr[j], acc[i][j], 0, 0, 0);                             \
        }                                                                               \
        FENCE();                                                                        \
        __builtin_amdgcn_s_barrier();                                                   \
        FENCE();                                                                        \
    }

// ---------- gemm_occ2: BM=256, BN=64, BK=64, 256 thr (4 waves), 2 blocks/CU ----------
// 80 KB LDS; counted vmcnt(10) keeps next tile's 10 loads in flight across
// raw barriers; XOR swizzle (row&7)<<4 on 128B rows = conflict-free ds_read.
// EPI 0: bf16 + bias[row]; EPI 1: f32 + bias[row] (per-batch via bias_bstride).
template <int EPI>
__global__ __launch_bounds__(256, 2) void gemm_occ2(
    const unsigned short* __restrict__ A, const unsigned short* __restrict__ B,
    long long strideA, long long strideB,
    const float* __restrict__ bias, int bias_bstride,
    void* __restrict__ Cout, int ldc, long long strideC,
    int gx, int gy)
{
    __shared__ unsigned short smem[2 * (ASZA3 + ASZB3)];   // 80 KB

    int bx, by, n;  swz3(gx, gy, bx, by, n);   // by (M-tile) fastest
    const int m0 = by * 256;
    const int n0 = bx * 64;

    const unsigned short* Ab = A + (size_t)n * strideA + (size_t)m0 * CIN;
    const unsigned short* Bb = B + (size_t)n * strideB + (size_t)n0 * CIN;

    const int t    = threadIdx.x;
    const int lane = t & 63;
    const int wave = t >> 6;          // 0..3 -> rows wave*64..+64
    const int wr   = wave * 64;
    const int l15  = lane & 15;
    const int l16  = lane >> 4;

    f32x4_t acc[4][4] = {};

    auto stage = [&](int k0, int b) {
        unsigned short* Asb = smem + b * (ASZA3 + ASZB3);
        unsigned short* Bsb = Asb + ASZA3;
        #pragma unroll
        for (int c = 0; c < 8; ++c) {       // A: 32 KB (256 rows x 128 B)
            const int o   = (c * 256 + t) * 16;
            const int row = o >> 7;
            const int ce  = ((o & 127) ^ ((row & 7) << 4)) >> 1;
            __builtin_amdgcn_global_load_lds(
                AS1(Ab + (size_t)row * CIN + k0 + ce), AS3((char*)Asb + o), 16, 0, 0);
        }
        #pragma unroll
        for (int c = 0; c < 2; ++c) {       // B: 8 KB (64 rows x 128 B)
            const int o   = (c * 256 + t) * 16;
            const int row = o >> 7;
            const int ce  = ((o & 127) ^ ((row & 7) << 4)) >> 1;
            __builtin_amdgcn_global_load_lds(
                AS1(Bb + (size_t)row * CIN + k0 + ce), AS3((char*)Bsb + o), 16, 0, 0);
        }
    };

    const int NT = CIN / 64;   // K = 512
    stage(0, 0);
    for (int itk = 0; itk < NT; ++itk) {
        const int cur = itk & 1;
        if (itk + 1 < NT) {
            stage((itk + 1) * 64, cur ^ 1);
            asm volatile("s_waitcnt vmcnt(10)" ::: "memory");
        } else {
            asm volatile("s_waitcnt vmcnt(0)" ::: "memory");
        }
        __builtin_amdgcn_s_barrier();
        FENCE();
        const char* Asb = (const char*)(smem + cur * (ASZA3 + ASZB3));
        const char* Bsb = Asb + 2 * ASZA3;
        const int swz = (l15 & 7) << 4;
        #pragma unroll
        for (int ks = 0; ks < 2; ++ks) {
            const int cb = (ks * 64 + l16 * 16) ^ swz;
            bf16x8_t af[4], bfr[4];
            #pragma unroll
            for (int i = 0; i < 4; ++i)
                af[i] = *(const bf16x8_t*)(Asb + (wr + i * 16 + l15) * 128 + cb);
            #pragma unroll
            for (int j = 0; j < 4; ++j)
                bfr[j] = *(const bf16x8_t*)(Bsb + (j * 16 + l15) * 128 + cb);
            #pragma unroll
            for (int i = 0; i < 4; ++i)
                #pragma unroll
                for (int j = 0; j < 4; ++j)
                    acc[i][j] = __builtin_amdgcn_mfma_f32_16x16x32_bf16(
                        af[i], bfr[j], acc[i][j], 0, 0, 0);
        }
        FENCE();
        __builtin_amdgcn_s_barrier();
        FENCE();
    }

    // epilogue: 8 passes of 32 rows x 64 cols via LDS repack (fbuf 32x68 f32)
    float* fbuf = (float*)smem;
    const size_t cbase = (size_t)n * strideC;
    const float* beff = bias + (size_t)n * bias_bstride;
    #pragma unroll
    for (int p = 0; p < 8; ++p) {
        __syncthreads();
        if (wave == (p >> 1)) {
            #pragma unroll
            for (int i2 = 0; i2 < 2; ++i2) {
                const int i = (p & 1) * 2 + i2;
                #pragma unroll
                for (int r = 0; r < 4; ++r) {
                    const int lrow = i2 * 16 + l16 * 4 + r;
                    #pragma unroll
                    for (int j = 0; j < 4; ++j)
                        fbuf[lrow * 68 + j * 16 + l15] = acc[i][j][r];
                }
            }
        }
        __syncthreads();
        const int lrow = t >> 3;           // 0..31
        const int col  = (t & 7) * 8;      // 0..56
        const int row  = m0 + p * 32 + lrow;
        float v[8];
        *(float4*)&v[0] = *(const float4*)&fbuf[lrow * 68 + col];
        *(float4*)&v[4] = *(const float4*)&fbuf[lrow * 68 + col + 4];
        const float badd = beff[row];
        const size_t idx = cbase + (size_t)row * ldc + n0 + col;
        if constexpr (EPI == 1) {
            float o[8];
            #pragma unroll
            for (int k = 0; k < 8; ++k) o[k] = v[k] + badd;
            float* op = (float*)Cout + idx;
            *(float4*)op = *(const float4*)&o[0];
            *(float4*)(op + 4) = *(const float4*)&o[4];
        } else {
            unsigned short o[8];
            #pragma unroll
            for (int k = 0; k < 8; ++k) o[k] = f2b(v[k] + badd);
            *(short8_t*)((unsigned short*)Cout + idx) = *(const short8_t*)o;
        }
    }
}

// ---------- scores GEMM, split-K=4 (128-tile) ----------
__global__ __launch_bounds__(256) void gemm_scores(
    const unsigned short* __restrict__ Ysp, float* __restrict__ scoresP)
{
    __shared__ unsigned short smem[4 * ASZ];

    int bx, by, z;  swz3(MMID / 128, MMID / 128, bx, by, z);
    const int n  = z >> 2;
    const int kc = z & 3;
    const int m0 = by * 128;
    const int n0 = bx * 128;

    const unsigned short* Ab = Ysp + (size_t)n * CIN * HW + (size_t)m0 * HW;
    const unsigned short* Bb = Ysp + (size_t)n * CIN * HW + (size_t)(MMID + n0) * HW;

    const int t    = threadIdx.x;
    const int lane = t & 63;
    const int wave = t >> 6;
    const int wr   = (wave >> 1) * 64;
    const int wc   = (wave & 1) * 64;
    const int l15  = lane & 15;
    const int l16  = lane >> 4;

    f32x4_t acc[4][4] = {};
    const int kbeg = kc * (HW / KSPLIT);
    GEMM_KLOOP(Ab, Bb, HW, HW, kbeg, (HW / KSPLIT) / 64)

    float* outp = scoresP + (size_t)(kc * NB + n) * MMID * MMID;
    epilogue_repack<1>(acc, smem, m0, n0, wave, lane, outp, MMID, 0);
}

// ---------- softmax over rows (reduces KSPLIT partials, scale 1/64) ----------
__global__ __launch_bounds__(256) void softmax_rows(
    const float* __restrict__ scoresP, unsigned short* __restrict__ attn)
{
    const int wave = threadIdx.x >> 6;
    const int l    = threadIdx.x & 63;
    const size_t row = (size_t)blockIdx.x * 4 + wave;
    const size_t pstride = (size_t)NB * MMID * MMID;
    float4 v = {0.f, 0.f, 0.f, 0.f};
    #pragma unroll
    for (int p = 0; p < KSPLIT; ++p) {
        float4 u = *(const float4*)(scoresP + p * pstride + row * MMID + l * 4);
        v.x += u.x; v.y += u.y; v.z += u.z; v.w += u.w;
    }
    float mx = fmaxf(fmaxf(v.x, v.y), fmaxf(v.z, v.w));
    #pragma unroll
    for (int off = 32; off; off >>= 1) mx = fmaxf(mx, __shfl_xor(mx, off));
    const float sc = 0.015625f;               // 1/64
    float e0 = __expf((v.x - mx) * sc), e1 = __expf((v.y - mx) * sc);
    float e2 = __expf((v.z - mx) * sc), e3 = __expf((v.w - mx) * sc);
    float sum = e0 + e1 + e2 + e3;
    #pragma unroll
    for (int off = 32; off; off >>= 1) sum += __shfl_xor(sum, off);
    const float inv = 1.0f / sum;
    unsigned short o[4] = { f2b(e0 * inv), f2b(e1 * inv), f2b(e2 * inv), f2b(e3 * inv) };
    *(uint64_t*)(attn + row * MMID + l * 4) = *(const uint64_t*)o;
}

// ---------- vec[n][c] = be[c] + sum_k G[n][c][k] * bp[k] ----------
__global__ __launch_bounds__(256) void compute_vec(
    const unsigned short* __restrict__ G, const float* __restrict__ bsp,
    const float* __restrict__ be, float* __restrict__ vec)
{
    const int n = blockIdx.x >> 1;
    const int c = ((blockIdx.x & 1) << 8) + threadIdx.x;
    const unsigned short* g = G + ((size_t)n * CIN + c) * MMID;
    float s = 0.f;
    for (int k = 0; k < MMID; k += 8) {
        short8_t v = *(const short8_t*)(g + k);
        #pragma unroll
        for (int j = 0; j < 8; ++j)
            s += b2f((unsigned short)v[j]) * bsp[MMID + k + j];
    }
    vec[n * CIN + c] = be[c] + s;
}

// ---------- NT GEMM (128-tile): D[m][n] = sum_k A[m][k] * B[n][k] ----------
template <int EPI>
__global__ __launch_bounds__(256) void gemm_nt(
    const unsigned short* __restrict__ A, const unsigned short* __restrict__ B,
    int lda, int ldb, int K,
    long long strideA, long long strideB,
    void* __restrict__ Cout, int ldc, long long strideC,
    int gx, int gy)
{
    __shared__ unsigned short smem[4 * ASZ];

    int bx, by, n;  swz3(gx, gy, bx, by, n);
    const int m0 = by * 128;
    const int n0 = bx * 128;

    const unsigned short* Ab = A + (size_t)n * strideA + (size_t)m0 * lda;
    const unsigned short* Bb = B + (size_t)n * strideB + (size_t)n0 * ldb;

    const int t    = threadIdx.x;
    const int lane = t & 63;
    const int wave = t >> 6;
    const int wr   = (wave >> 1) * 64;
    const int wc   = (wave & 1) * 64;
    const int l15  = lane & 15;
    const int l16  = lane >> 4;

    f32x4_t acc[4][4] = {};
    GEMM_KLOOP(Ab, Bb, lda, ldb, 0, K / 64)

    epilogue_repack<EPI>(acc, smem, m0, n0, wave, lane,
                         Cout, ldc, (size_t)n * strideC);
}

// ---------- launch ----------
extern "C" void kernel_launch(void* const* d_in, const int* in_sizes, int n_in,
                              void* d_out, int out_size, void* d_ws, size_t ws_size,
                              hipStream_t stream)
{
    const float* x   = (const float*)d_in[0];
    const float* Ws  = (const float*)d_in[1];
    const float* bs  = (const float*)d_in[2];
    const float* Wp  = (const float*)d_in[3];
    const float* bp  = (const float*)d_in[4];
    const float* Wef = (const float*)d_in[5];
    const float* be  = (const float*)d_in[6];
    float* out = (float*)d_out;

    unsigned short* xT   = (unsigned short*)d_ws;                         // [16][4096][512] bf16
    unsigned short* Ysp  = xT   + (size_t)NB * HW * CIN;                  // [16][512][4096] bf16
    unsigned short* Wsp  = Ysp  + (size_t)NB * CIN * HW;                  // [512][512] bf16
    unsigned short* Wex  = Wsp  + (size_t)CIN * CIN;                      // [512][256] bf16
    unsigned short* WpT  = Wex  + (size_t)CIN * MMID;                     // [512][256] bf16
    unsigned short* attn = WpT  + (size_t)CIN * MMID;                     // [16][256][256] bf16
    unsigned short* attnT= attn + (size_t)NB * MMID * MMID;               // [16][256][256] bf16
    unsigned short* G    = attnT+ (size_t)NB * MMID * MMID;               // [16][512][256] bf16
    unsigned short* Meff = G    + (size_t)NB * CIN * MMID;                // [16][512][512] bf16
    float* scoresP = (float*)(Meff + (size_t)NB * CIN * CIN);             // [4][16][256][256] f32
    float* bsp = scoresP + (size_t)KSPLIT * NB * MMID * MMID;             // [512]
    float* vec = bsp + CIN;                                               // [16][512]

    prep_weights<<<512, 256, 0, stream>>>(Ws, Wp, Wef, bs, bp, Wsp, Wex, WpT, bsp);

    transpose_convert_x<<<dim3(HW / 64, CIN / 64, NB), 256, 0, stream>>>(x, xT);

    // Ysp[mm][h] = Wsp[mm][c].xT[h][c] + bsp[mm]   (BM=256, BN=64, 2 blocks/CU)
    gemm_occ2<0><<<(CIN / 256) * (HW / 64) * NB, 256, 0, stream>>>(
        Wsp, xT, 0LL, (long long)HW * CIN,
        bsp, 0, Ysp, HW, (long long)CIN * HW,
        HW / 64, CIN / 256);

    // scores partials, split-K=4
    gemm_scores<<<(MMID / 128) * (MMID / 128) * NB * KSPLIT, 256, 0, stream>>>(
        Ysp, scoresP);

    softmax_rows<<<NB * MMID / 4, 256, 0, stream>>>(scoresP, attn);

    // attnT[k][m] = attn[m][k]
    transpose_bf16_64<<<dim3(MMID / 64, MMID / 64, NB), 256, 0, stream>>>(
        attn, attnT, MMID, MMID, (long long)MMID * MMID, (long long)MMID * MMID);

    // G[c][k] = Wex[c][m] . attnT[k][m]   (M=512, N=256, K=256) = W_ext @ attn
    gemm_nt<2><<<(MMID / 128) * (CIN / 128) * NB, 256, 0, stream>>>(
        Wex, attnT, MMID, MMID, MMID,
        0LL, (long long)MMID * MMID,
        G, MMID, (long long)CIN * MMID,
        MMID / 128, CIN / 128);

    // vec[n][c] = be[c] + G[n][c][:] . bp
    compute_vec<<<NB * 2, 256, 0, stream>>>(G, bsp, be, vec);

    // Meff[c][c'] = G[c][k].WpT[c'][k] + I   (residual folded into diagonal)
    gemm_nt<4><<<(CIN / 128) * (CIN / 128) * NB, 256, 0, stream>>>(
        G, WpT, MMID, MMID, MMID,
        (long long)CIN * MMID, 0LL,
        Meff, CIN, (long long)CIN * CIN,
        CIN / 128, CIN / 128);

    // out[c][h] = (Meff+I)[c][c'] . xT[h][c'] + vec[n][c]   (f32 store)
    gemm_occ2<1><<<(CIN / 256) * (HW / 64) * NB, 256, 0, stream>>>(
        Meff, xT, (long long)CIN * CIN, (long long)HW * CIN,
        vec, CIN, out, HW, (long long)CIN * HW,
        HW / 64, CIN / 256);
}